// Round 16
// baseline (364.261 us; speedup 1.0000x reference)
//
#include <hip/hip_runtime.h>
#include <math.h>

#define B_ 4
#define N_ 4096
#define C_ 64
#define K1_ 4
#define K2_ 6
#define EPS_ 1e-5f
#define BN_ (B_ * N_)
#define NCH_ 8
#define CHP_ 512

typedef __attribute__((ext_vector_type(8))) short bf16x8;
typedef __attribute__((ext_vector_type(4))) float f32x4;
typedef __attribute__((ext_vector_type(2))) float f32x2;

__device__ __forceinline__ unsigned short f2bf(float f) {
  unsigned int u = __float_as_uint(f);
  unsigned int r = (u + 0x7fffu + ((u >> 16) & 1u)) >> 16;
  return (unsigned short)r;
}
__device__ __forceinline__ float bf2f(unsigned short u) {
  return __uint_as_float(((unsigned int)u) << 16);
}
__device__ __forceinline__ void unpack8(uint4 u, float* f) {
  unsigned* up = (unsigned*)&u;
#pragma unroll
  for (int w = 0; w < 4; ++w) {
    f[2 * w] = __uint_as_float(up[w] << 16);
    f[2 * w + 1] = __uint_as_float(up[w] & 0xFFFF0000u);
  }
}

template <int K>
__device__ __forceinline__ void insKi(int* kd, int k) {
  int x = k;
#pragma unroll
  for (int u = 0; u < K; ++u) {
    int lo = min(kd[u], x);
    x = max(kd[u], x);
    kd[u] = lo;
  }
}

// ---------------- init: weight conversion + pose/tables + zeroing --------------
__global__ __launch_bounds__(256) void k_init(
    const float* __restrict__ w1_0, const float* __restrict__ w1_1,
    const float* __restrict__ w1_2, const float* __restrict__ w2_0,
    const float* __restrict__ w2_1, unsigned short* __restrict__ Wf2a,
    unsigned short* __restrict__ Wf1a, unsigned short* __restrict__ Wfe,
    unsigned short* __restrict__ Wf1b, unsigned short* __restrict__ wb1,
    unsigned short* __restrict__ wb2, unsigned short* __restrict__ wb4,
    const float* __restrict__ pos1, const float* __restrict__ pos2,
    const float* __restrict__ qc, const float* __restrict__ tc,
    float4* __restrict__ pts4w, float4* __restrict__ pts4p,
    float4* __restrict__ pairW, float4* __restrict__ pairP,
    float* __restrict__ zbase) {
  int t = blockIdx.x * 256 + threadIdx.x;
  int m = blockIdx.y;
  if (m < 7) {
    switch (m) {
      case 0:
        if (t < 8192) Wf2a[t] = f2bf(w1_0[(t >> 6) * 131 + 3 + (t & 63)]);
        break;
      case 1:
        if (t < 8192) Wf1a[t] = f2bf(w1_0[(t >> 6) * 131 + 67 + (t & 63)]);
        break;
      case 2:
        if (t < 8192) Wfe[t] = f2bf(w2_0[(t >> 6) * 131 + 3 + (t & 63)]);
        break;
      case 3:
        if (t < 8192) Wf1b[t] = f2bf(w2_0[(t >> 6) * 131 + 67 + (t & 63)]);
        break;
      case 4:
        if (t < 8192) wb1[t] = f2bf(w1_1[t]);
        break;
      case 5:
        if (t < 4096) wb2[t] = f2bf(w1_2[t]);
        break;
      default:
        if (t < 8192) wb4[t] = f2bf(w2_1[t]);
        break;
    }
    return;
  }
  if (m == 8) {
    if (t < 10240) zbase[t] = 0.f;  // stat(8192) + pooled(2048)
    return;
  }
  if (t >= BN_) return;
  int b = t / N_;
  float qw = qc[b * 4 + 0], qx = qc[b * 4 + 1], qy = qc[b * 4 + 2], qz = qc[b * 4 + 3];
  float vx = pos1[t * 3 + 0], vy = pos1[t * 3 + 1], vz = pos1[t * 3 + 2];
  float aw = -(qx * vx + qy * vy + qz * vz);
  float ax = qw * vx + qy * vz - qz * vy;
  float ay = qw * vy - qx * vz + qz * vx;
  float az = qw * vz + qx * vy - qy * vx;
  float n2 = qw * qw + qx * qx + qy * qy + qz * qz + 1e-10f;
  float bw = qw / n2, bx = -qx / n2, by = -qy / n2, bz = -qz / n2;
  float rx = aw * bx + ax * bw + ay * bz - az * by;
  float ry = aw * by - ax * bz + ay * bw + az * bx;
  float rz = aw * bz + ax * by - ay * bx + az * bw;
  rx += tc[b * 3 + 0];
  ry += tc[b * 3 + 1];
  rz += tc[b * 3 + 2];
  float rw2 = rx * rx + ry * ry + rz * rz;
  pts4w[t] = make_float4(rx, ry, rz, rw2);
  int p = t >> 1, h = t & 1;
  float* bwp = (float*)&pairW[(size_t)2 * p];
  bwp[0 + h] = rx; bwp[2 + h] = ry; bwp[4 + h] = rz; bwp[6 + h] = rw2;
  float px = pos2[t * 3 + 0], py = pos2[t * 3 + 1], pz = pos2[t * 3 + 2];
  float pw2 = px * px + py * py + pz * pz;
  pts4p[t] = make_float4(px, py, pz, pw2);
  float* bpp = (float*)&pairP[(size_t)2 * p];
  bpp[0 + h] = px; bpp[2 + h] = py; bpp[4 + h] = pz; bpp[6 + h] = pw2;
}

// ---------------- shared MFMA 64x128x64 tail (bf16 output) ---------------------
__device__ __forceinline__ void proj_mfma_tail(const unsigned short* Xs, int tid,
                                               int row0,
                                               const unsigned short* __restrict__ Wb,
                                               unsigned short* __restrict__ dst) {
  constexpr int SP = 72;
  int l = tid & 63, wv = tid >> 6;
  int lm = l & 15, quad = l >> 4;
  int n0 = wv * 32;
  f32x4 acc[4][2];
#pragma unroll
  for (int rt = 0; rt < 4; ++rt)
#pragma unroll
    for (int ct = 0; ct < 2; ++ct) acc[rt][ct] = (f32x4)(0.f);
#pragma unroll
  for (int k0 = 0; k0 < 64; k0 += 32) {
    bf16x8 a[4], b[2];
#pragma unroll
    for (int rt = 0; rt < 4; ++rt)
      a[rt] = *(const bf16x8*)&Xs[(rt * 16 + lm) * SP + k0 + quad * 8];
#pragma unroll
    for (int ct = 0; ct < 2; ++ct)
      b[ct] = *(const bf16x8*)&Wb[(size_t)(n0 + ct * 16 + lm) * 64 + k0 + quad * 8];
#pragma unroll
    for (int rt = 0; rt < 4; ++rt)
#pragma unroll
      for (int ct = 0; ct < 2; ++ct)
        acc[rt][ct] =
            __builtin_amdgcn_mfma_f32_16x16x32_bf16(a[rt], b[ct], acc[rt][ct], 0, 0, 0);
  }
#pragma unroll
  for (int rt = 0; rt < 4; ++rt)
#pragma unroll
    for (int ct = 0; ct < 2; ++ct)
#pragma unroll
      for (int r = 0; r < 4; ++r) {
        int row = row0 + rt * 16 + quad * 4 + r;
        dst[(size_t)row * 128 + n0 + ct * 16 + lm] = f2bf(acc[rt][ct][r]);
      }
}

// ---------------- KNN chunk body: unconditional branchless bubble insert -------
// R15 lesson: LDS stack + ballot-gated drains cost ~41 VALU/pair (divergent
// drains pay wave-max ptr). With the 12-op bubble insert, unconditional
// insertion per candidate is cheaper and divergence-free (~15 VALU/pair).
template <int K>
__device__ __forceinline__ void knn_chunk(const f32x4* __restrict__ PT, int base,
                                          float4 qv, int* __restrict__ orow) {
  f32x2 qq2 = (f32x2)(qv.w);
  f32x2 m2x = (f32x2)(-2.f * qv.x);
  f32x2 m2y = (f32x2)(-2.f * qv.y);
  f32x2 m2z = (f32x2)(-2.f * qv.z);
  int kd[K];
#pragma unroll
  for (int t = 0; t < K; ++t) kd[t] = 0x7fffffff;
  for (int jj = 0; jj < CHP_; jj += 8) {
    f32x2 d[4];
#pragma unroll
    for (int gq = 0; gq < 2; ++gq) {
      f32x4 e0 = PT[jj + gq * 4 + 0];
      f32x4 e1 = PT[jj + gq * 4 + 1];
      f32x4 e2 = PT[jj + gq * 4 + 2];
      f32x4 e3 = PT[jj + gq * 4 + 3];
      d[gq * 2 + 0] = __builtin_elementwise_fma(
          m2x, e0.xy,
          __builtin_elementwise_fma(m2y, e0.zw,
                                    __builtin_elementwise_fma(m2z, e1.xy, e1.zw + qq2)));
      d[gq * 2 + 1] = __builtin_elementwise_fma(
          m2x, e2.xy,
          __builtin_elementwise_fma(m2y, e2.zw,
                                    __builtin_elementwise_fma(m2z, e3.xy, e3.zw + qq2)));
    }
    int j0 = base + jj;
#pragma unroll
    for (int p = 0; p < 4; ++p) {
      int ka = (int)((__float_as_uint(d[p].x) & 0xFFFFF000u) | (unsigned)(j0 + 2 * p));
      int kb = (int)((__float_as_uint(d[p].y) & 0xFFFFF000u) | (unsigned)(j0 + 2 * p + 1));
      insKi<K>(kd, ka);
      insKi<K>(kd, kb);
    }
  }
#pragma unroll
  for (int t = 0; t < K; ++t) orow[t] = kd[t];
}

// ---------------- fused: 3x proj GEMM + dual-KNN -------------------------------
__global__ __launch_bounds__(256) void k_knnproj(
    const float4* __restrict__ pts4w, const float4* __restrict__ pairW,
    const float4* __restrict__ pairP, int* __restrict__ outK,
    const float* __restrict__ feat2, const unsigned short* __restrict__ Wf2a,
    unsigned short* __restrict__ P2a, const float* __restrict__ feat1,
    const unsigned short* __restrict__ Wf1a, unsigned short* __restrict__ P1a,
    const unsigned short* __restrict__ Wf1b, unsigned short* __restrict__ P1b) {
  __shared__ unsigned short Xs[64 * 72];  // proj staging only (9216 B)
  int tid = threadIdx.x;
  int bid = blockIdx.x;
  if (bid < 768) {
    const float* src;
    const unsigned short* Wb;
    unsigned short* dst;
    switch (bid >> 8) {
      case 0: src = feat2; Wb = Wf2a; dst = P2a; break;
      case 1: src = feat1; Wb = Wf1a; dst = P1a; break;
      default: src = feat1; Wb = Wf1b; dst = P1b; break;
    }
    int row0 = (bid & 255) * 64;
    for (int e = tid; e < 64 * 16; e += 256) {
      int r = e >> 4, s = e & 15;
      float4 v = *(const float4*)&src[(size_t)(row0 + r) * 64 + s * 4];
      ushort4 o;
      o.x = f2bf(v.x); o.y = f2bf(v.y); o.z = f2bf(v.z); o.w = f2bf(v.w);
      *(ushort4*)&Xs[r * 72 + s * 4] = o;
    }
    __syncthreads();
    proj_mfma_tail(Xs, tid, row0, Wb, dst);
    return;
  }
  int kbid = bid - 768;
  int x = kbid & 15, y = (kbid >> 4) & 7, z = kbid >> 7;
  int b = z & 3;
  int which = z >> 2;
  const f32x4* __restrict__ PT =
      (const f32x4*)((which ? pairW : pairP) + (size_t)b * N_ + y * CHP_);
  int base = y * CHP_;
  int n = x * 256 + tid;
  float4 qv = pts4w[(size_t)b * N_ + n];
  int* orow = &outK[((size_t)which * BN_ * NCH_ + (size_t)(b * N_ + n) * NCH_ + y) * 6];
  if (which == 0)
    knn_chunk<6>(PT, base, qv, orow);
  else
    knn_chunk<4>(PT, base, qv, orow);
}

// ---------------- fused fe + projection ----------------------------------------
__global__ __launch_bounds__(256) void k_feproj(const unsigned short* __restrict__ y3,
                                                const float* __restrict__ stat,
                                                const float* __restrict__ g,
                                                const float* __restrict__ bb,
                                                const unsigned short* __restrict__ Wfe,
                                                unsigned short* __restrict__ Pfe) {
  constexpr int SP = 72;
  __shared__ unsigned short Xs[64 * SP];
  __shared__ float scl[C_], shf[C_];
  int tid = threadIdx.x;
  if (tid < C_) {
    int c = tid;
    float s = 0.f, s2 = 0.f;
#pragma unroll
    for (int u = 0; u < 8; ++u) {
      s += stat[c * 8 + u];
      s2 += stat[C_ * 8 + c * 8 + u];
    }
    const float invM = 1.f / (float)(BN_ * K2_);
    float m = s * invM;
    float v = s2 * invM - m * m;
    float sc = g[c] * rsqrtf(v + EPS_);
    scl[c] = sc;
    shf[c] = bb[c] - m * sc;
  }
  __syncthreads();
  int row0 = blockIdx.x * 64;
  for (int e = tid; e < 64 * 16; e += 256) {
    int r = e >> 4, s = e & 15;
    size_t base = ((size_t)(row0 + r) * K2_) * C_ + s * 4;
    float a0 = 0.f, a1 = 0.f, a2 = 0.f, a3 = 0.f;
#pragma unroll
    for (int k = 0; k < K2_; ++k) {
      ushort4 u = *(const ushort4*)&y3[base + (size_t)k * C_];
      a0 += fmaxf(fmaf(bf2f(u.x), scl[s * 4 + 0], shf[s * 4 + 0]), 0.f);
      a1 += fmaxf(fmaf(bf2f(u.y), scl[s * 4 + 1], shf[s * 4 + 1]), 0.f);
      a2 += fmaxf(fmaf(bf2f(u.z), scl[s * 4 + 2], shf[s * 4 + 2]), 0.f);
      a3 += fmaxf(fmaf(bf2f(u.w), scl[s * 4 + 3], shf[s * 4 + 3]), 0.f);
    }
    ushort4 o;
    o.x = f2bf(a0); o.y = f2bf(a1); o.z = f2bf(a2); o.w = f2bf(a3);
    *(ushort4*)&Xs[r * SP + s * 4] = o;
  }
  __syncthreads();
  proj_mfma_tail(Xs, tid, row0, Wfe, Pfe);
}

// ---------------- stat0: merge knnK -> idxM (gj) + BN stats of y0 --------------
template <int KNN>
__global__ __launch_bounds__(256) void k_stat0(
    const float* __restrict__ Wfull, const float4* __restrict__ nbrPts,
    const float4* __restrict__ qryPts, const unsigned short* __restrict__ Pj,
    const unsigned short* __restrict__ Pn, const int* __restrict__ outK,
    int* __restrict__ idxM, float* __restrict__ statOut) {
  __shared__ float Wx[3][128];
  __shared__ float red[16][128];
  __shared__ int idxL[33][6];
  int tid = threadIdx.x;
  int row0 = blockIdx.x * 128;
  int first = row0 / KNN;
  int nq = (row0 + 127) / KNN - first + 1;
  if (tid < 128) {
    Wx[0][tid] = Wfull[tid * 131 + 0];
    Wx[1][tid] = Wfull[tid * 131 + 1];
    Wx[2][tid] = Wfull[tid * 131 + 2];
  }
  if (tid < nq) {
    int q = first + tid;
    int km[6];
#pragma unroll
    for (int u = 0; u < 6; ++u) km[u] = 0x7fffffff;
    size_t ib = (size_t)q * (NCH_ * 6);
    if (KNN == 6) {
      for (int c = 0; c < NCH_ * 6; ++c) insKi<6>(km, outK[ib + c]);
    } else {
      for (int ch = 0; ch < NCH_; ++ch)
#pragma unroll
        for (int u = 0; u < 4; ++u) insKi<4>(km, outK[ib + ch * 6 + u]);
    }
    int bb = (q >> 12) << 12;
#pragma unroll
    for (int u = 0; u < KNN; ++u) {
      int gj = bb + (km[u] & 0xFFF);
      idxL[tid][u] = gj;
      idxM[(size_t)q * KNN + u] = gj;
    }
  }
  __syncthreads();
  int cg = tid & 15, rg = tid >> 4;
  int c0 = cg * 8;
  float wx0[8], wx1[8], wx2[8];
#pragma unroll
  for (int u = 0; u < 8; ++u) {
    wx0[u] = Wx[0][c0 + u];
    wx1[u] = Wx[1][c0 + u];
    wx2[u] = Wx[2][c0 + u];
  }
  float s1[8], s2[8];
#pragma unroll
  for (int u = 0; u < 8; ++u) { s1[u] = 0.f; s2[u] = 0.f; }
#pragma unroll
  for (int i = 0; i < 8; ++i) {
    int row = row0 + rg * 8 + i;
    int g = row / KNN;
    int gj = idxL[g - first][row - g * KNN];
    float4 pw = qryPts[g];
    float4 pn4 = nbrPts[gj];
    float xd0 = pn4.x - pw.x;
    float xd1 = pn4.y - pw.y;
    float xd2 = pn4.z - pw.z;
    uint4 uj = *(const uint4*)&Pj[(size_t)gj * 128 + c0];
    uint4 un = *(const uint4*)&Pn[(size_t)g * 128 + c0];
    float yj[8], yn[8];
    unpack8(uj, yj);
    unpack8(un, yn);
#pragma unroll
    for (int u = 0; u < 8; ++u) {
      float v = yj[u] + yn[u];
      v = fmaf(xd0, wx0[u], v);
      v = fmaf(xd1, wx1[u], v);
      v = fmaf(xd2, wx2[u], v);
      s1[u] += v;
      s2[u] = fmaf(v, v, s2[u]);
    }
  }
  int slot = blockIdx.x & 7;
#pragma unroll
  for (int u = 0; u < 8; ++u) red[rg][c0 + u] = s1[u];
  __syncthreads();
  if (tid < 128) {
    float s = 0.f;
#pragma unroll
    for (int r = 0; r < 16; ++r) s += red[r][tid];
    atomicAdd(&statOut[tid * 8 + slot], s);
  }
  __syncthreads();
#pragma unroll
  for (int u = 0; u < 8; ++u) red[rg][c0 + u] = s2[u];
  __syncthreads();
  if (tid < 128) {
    float s = 0.f;
#pragma unroll
    for (int r = 0; r < 16; ++r) s += red[r][tid];
    atomicAdd(&statOut[128 * 8 + tid * 8 + slot], s);
  }
}

// ---------------- layerG: recompute y0 from P + bn/relu -> MFMA (128->64) ------
template <int KNN>
__global__ __launch_bounds__(256) void k_layerG(
    const unsigned short* __restrict__ Wb,  // [64][128] bf16
    const float* __restrict__ Wfull, const float4* __restrict__ nbrPts,
    const float4* __restrict__ qryPts, const unsigned short* __restrict__ Pj,
    const unsigned short* __restrict__ Pn, const int* __restrict__ idxM,
    const float* __restrict__ statPrev, const float* __restrict__ gPrev,
    const float* __restrict__ bPrev, float prevInvM,
    unsigned short* __restrict__ yout,  // [rows][64] bf16
    float* __restrict__ statOut) {
  constexpr int KP = 128, COUT = 64;
  constexpr int SP = KP + 8;
  constexpr int CST = COUT + 8;
  __shared__ unsigned short Xs[64 * SP];
  __shared__ float scl[KP];
  __shared__ float shf[KP];
  __shared__ float Wx[3][128];
  __shared__ int gjL[64];
  __shared__ float xdL[3][64];

  int tid = threadIdx.x;
  int row0 = blockIdx.x * 64;

  for (int c = tid; c < KP; c += 256) {
    float s = 0.f, s2 = 0.f;
#pragma unroll
    for (int u = 0; u < 8; ++u) {
      s += statPrev[c * 8 + u];
      s2 += statPrev[KP * 8 + c * 8 + u];
    }
    float m = s * prevInvM;
    float v = s2 * prevInvM - m * m;
    float sc = gPrev[c] * rsqrtf(v + EPS_);
    scl[c] = sc;
    shf[c] = bPrev[c] - m * sc;
  }
  if (tid < 128) {
    Wx[0][tid] = Wfull[tid * 131 + 0];
    Wx[1][tid] = Wfull[tid * 131 + 1];
    Wx[2][tid] = Wfull[tid * 131 + 2];
  }
  if (tid < 64) {
    int row = row0 + tid;
    int g = row / KNN;
    int gj = idxM[(size_t)g * KNN + (row - g * KNN)];
    gjL[tid] = gj;
    float4 pw = qryPts[g];
    float4 pn4 = nbrPts[gj];
    xdL[0][tid] = pn4.x - pw.x;
    xdL[1][tid] = pn4.y - pw.y;
    xdL[2][tid] = pn4.z - pw.z;
  }
  __syncthreads();
  for (int e = tid; e < 64 * 16; e += 256) {
    int r = e >> 4, s = e & 15;
    int c0 = s * 8;
    int row = row0 + r;
    int g = row / KNN;
    uint4 uj = *(const uint4*)&Pj[(size_t)gjL[r] * 128 + c0];
    uint4 un = *(const uint4*)&Pn[(size_t)g * 128 + c0];
    float yj[8], yn[8];
    unpack8(uj, yj);
    unpack8(un, yn);
    float xd0 = xdL[0][r], xd1 = xdL[1][r], xd2 = xdL[2][r];
    unsigned short ob[8];
#pragma unroll
    for (int u = 0; u < 8; ++u) {
      int c = c0 + u;
      float v = yj[u] + yn[u];
      v = fmaf(xd0, Wx[0][c], v);
      v = fmaf(xd1, Wx[1][c], v);
      v = fmaf(xd2, Wx[2][c], v);
      ob[u] = f2bf(fmaxf(fmaf(v, scl[c], shf[c]), 0.f));
    }
    ushort4 o0, o1;
    o0.x = ob[0]; o0.y = ob[1]; o0.z = ob[2]; o0.w = ob[3];
    o1.x = ob[4]; o1.y = ob[5]; o1.z = ob[6]; o1.w = ob[7];
    *(ushort4*)&Xs[r * SP + c0] = o0;
    *(ushort4*)&Xs[r * SP + c0 + 4] = o1;
  }
  __syncthreads();

  int l = tid & 63, wv = tid >> 6;
  int lm = l & 15, quad = l >> 4;
  int n0 = wv * 16;

  f32x4 acc[4];
#pragma unroll
  for (int rt = 0; rt < 4; ++rt) acc[rt] = (f32x4)(0.f);

#pragma unroll
  for (int k0 = 0; k0 < KP; k0 += 32) {
    bf16x8 b = *(const bf16x8*)&Wb[(size_t)(n0 + lm) * KP + k0 + quad * 8];
#pragma unroll
    for (int rt = 0; rt < 4; ++rt) {
      bf16x8 a = *(const bf16x8*)&Xs[(rt * 16 + lm) * SP + k0 + quad * 8];
      acc[rt] = __builtin_amdgcn_mfma_f32_16x16x32_bf16(a, b, acc[rt], 0, 0, 0);
    }
  }

  int slot = blockIdx.x & 7;
  {
    float s1 = 0.f, s2 = 0.f;
#pragma unroll
    for (int rt = 0; rt < 4; ++rt)
#pragma unroll
      for (int r = 0; r < 4; ++r) {
        float v = acc[rt][r];
        s1 += v;
        s2 += v * v;
      }
    s1 += __shfl_xor(s1, 16);
    s1 += __shfl_xor(s1, 32);
    s2 += __shfl_xor(s2, 16);
    s2 += __shfl_xor(s2, 32);
    if (quad == 0) {
      int col = n0 + lm;
      atomicAdd(&statOut[col * 8 + slot], s1);
      atomicAdd(&statOut[COUT * 8 + col * 8 + slot], s2);
    }
  }

  __syncthreads();
  unsigned short* Ys = Xs;
#pragma unroll
  for (int rt = 0; rt < 4; ++rt)
#pragma unroll
    for (int r = 0; r < 4; ++r)
      Ys[(rt * 16 + quad * 4 + r) * CST + n0 + lm] = f2bf(acc[rt][r]);
  __syncthreads();
  for (int e = tid; e < 64 * 8; e += 256) {
    int r = e >> 3, c0 = (e & 7) * 8;
    uint4 v = *(const uint4*)&Ys[r * CST + c0];
    *(uint4*)&yout[((size_t)(row0 + r)) * COUT + c0] = v;
  }
}

// ---------------- PLAIN BN-relu + MFMA layer (64->64) --------------------------
__global__ __launch_bounds__(256) void k_layer64(
    const unsigned short* __restrict__ Wb,     // [64][64] bf16
    const unsigned short* __restrict__ yprev,  // [rows][64] bf16
    const float* __restrict__ statPrev, const float* __restrict__ gPrev,
    const float* __restrict__ bPrev, float prevInvM,
    unsigned short* __restrict__ yout, float* __restrict__ statOut) {
  constexpr int KP = 64, COUT = 64;
  constexpr int SP = KP + 8;
  constexpr int CST = COUT + 8;
  __shared__ unsigned short Xs[64 * SP];
  __shared__ float scl[KP];
  __shared__ float shf[KP];

  int tid = threadIdx.x;
  int row0 = blockIdx.x * 64;

  for (int c = tid; c < KP; c += 256) {
    float s = 0.f, s2 = 0.f;
#pragma unroll
    for (int u = 0; u < 8; ++u) {
      s += statPrev[c * 8 + u];
      s2 += statPrev[KP * 8 + c * 8 + u];
    }
    float m = s * prevInvM;
    float v = s2 * prevInvM - m * m;
    float sc = gPrev[c] * rsqrtf(v + EPS_);
    scl[c] = sc;
    shf[c] = bPrev[c] - m * sc;
  }
  __syncthreads();
  for (int e = tid; e < 64 * 8; e += 256) {
    int r = e >> 3, s = e & 7;
    int row = row0 + r;
    uint4 u = *(const uint4*)&yprev[(size_t)row * KP + s * 8];
    uint4 o;
    unsigned* up = (unsigned*)&u;
    unsigned* op = (unsigned*)&o;
#pragma unroll
    for (int w = 0; w < 4; ++w) {
      int c = s * 8 + w * 2;
      float lo = __uint_as_float(up[w] << 16);
      float hi = __uint_as_float(up[w] & 0xFFFF0000u);
      float rl = fmaxf(fmaf(lo, scl[c], shf[c]), 0.f);
      float rh = fmaxf(fmaf(hi, scl[c + 1], shf[c + 1]), 0.f);
      op[w] = (unsigned)f2bf(rl) | ((unsigned)f2bf(rh) << 16);
    }
    *(uint4*)&Xs[r * SP + s * 8] = o;
  }
  __syncthreads();

  int l = tid & 63, wv = tid >> 6;
  int lm = l & 15, quad = l >> 4;
  int n0 = wv * 16;

  f32x4 acc[4];
#pragma unroll
  for (int rt = 0; rt < 4; ++rt) acc[rt] = (f32x4)(0.f);
#pragma unroll
  for (int k0 = 0; k0 < KP; k0 += 32) {
    bf16x8 b = *(const bf16x8*)&Wb[(size_t)(n0 + lm) * KP + k0 + quad * 8];
#pragma unroll
    for (int rt = 0; rt < 4; ++rt) {
      bf16x8 a = *(const bf16x8*)&Xs[(rt * 16 + lm) * SP + k0 + quad * 8];
      acc[rt] = __builtin_amdgcn_mfma_f32_16x16x32_bf16(a, b, acc[rt], 0, 0, 0);
    }
  }

  int slot = blockIdx.x & 7;
  {
    float s1 = 0.f, s2 = 0.f;
#pragma unroll
    for (int rt = 0; rt < 4; ++rt)
#pragma unroll
      for (int r = 0; r < 4; ++r) {
        float v = acc[rt][r];
        s1 += v;
        s2 += v * v;
      }
    s1 += __shfl_xor(s1, 16);
    s1 += __shfl_xor(s1, 32);
    s2 += __shfl_xor(s2, 16);
    s2 += __shfl_xor(s2, 32);
    if (quad == 0) {
      int col = n0 + lm;
      atomicAdd(&statOut[col * 8 + slot], s1);
      atomicAdd(&statOut[COUT * 8 + col * 8 + slot], s2);
    }
  }

  __syncthreads();
  unsigned short* Ys = Xs;
#pragma unroll
  for (int rt = 0; rt < 4; ++rt)
#pragma unroll
    for (int r = 0; r < 4; ++r)
      Ys[(rt * 16 + quad * 4 + r) * CST + n0 + lm] = f2bf(acc[rt][r]);
  __syncthreads();
  for (int e = tid; e < 64 * 8; e += 256) {
    int r = e >> 3, c0 = (e & 7) * 8;
    uint4 v = *(const uint4*)&Ys[r * CST + c0];
    *(uint4*)&yout[((size_t)(row0 + r)) * COUT + c0] = v;
  }
}

// ---------------- pooled[b][c] = sum_{n,k} relu(bn(y5)) ------------------------
__global__ __launch_bounds__(256) void k_pooled(const unsigned short* __restrict__ y5,
                                                const float* __restrict__ stat,
                                                const float* __restrict__ g,
                                                const float* __restrict__ bb,
                                                float* __restrict__ pooled) {
  __shared__ float scl[C_], shf[C_];
  __shared__ float red[16][C_];
  if (threadIdx.x < C_) {
    int c = threadIdx.x;
    float s = 0.f, s2 = 0.f;
#pragma unroll
    for (int u = 0; u < 8; ++u) {
      s += stat[c * 8 + u];
      s2 += stat[C_ * 8 + c * 8 + u];
    }
    const float invM = 1.f / (float)(BN_ * K1_);
    float m = s * invM;
    float v = s2 * invM - m * m;
    float sc = g[c] * rsqrtf(v + EPS_);
    scl[c] = sc;
    shf[c] = bb[c] - m * sc;
  }
  __syncthreads();
  int cq = threadIdx.x & 15, rr = threadIdx.x >> 4;
  int c0 = cq * 4;
  int row0 = blockIdx.x * 64;
  int b = blockIdx.x >> 8;
  float a0 = 0.f, a1 = 0.f, a2 = 0.f, a3 = 0.f;
#pragma unroll
  for (int i = 0; i < 4; ++i) {
    int row = row0 + rr * 4 + i;
    ushort4 u = *(const ushort4*)&y5[(size_t)row * C_ + c0];
    a0 += fmaxf(fmaf(bf2f(u.x), scl[c0 + 0], shf[c0 + 0]), 0.f);
    a1 += fmaxf(fmaf(bf2f(u.y), scl[c0 + 1], shf[c0 + 1]), 0.f);
    a2 += fmaxf(fmaf(bf2f(u.z), scl[c0 + 2], shf[c0 + 2]), 0.f);
    a3 += fmaxf(fmaf(bf2f(u.w), scl[c0 + 3], shf[c0 + 3]), 0.f);
  }
  red[rr][c0 + 0] = a0;
  red[rr][c0 + 1] = a1;
  red[rr][c0 + 2] = a2;
  red[rr][c0 + 3] = a3;
  __syncthreads();
  if (threadIdx.x < C_) {
    float s = 0.f;
#pragma unroll
    for (int r = 0; r < 16; ++r) s += red[r][threadIdx.x];
    atomicAdd(&pooled[(b * C_ + threadIdx.x) * 8 + (blockIdx.x & 7)], s);
  }
}

// ---------------- head ---------------------------------------------------------
__global__ void k_final(const float* __restrict__ pooled, const float* __restrict__ wq,
                        const float* __restrict__ bq, const float* __restrict__ wt,
                        const float* __restrict__ bt, const float* __restrict__ qc,
                        const float* __restrict__ tc, float* __restrict__ out) {
  int b = threadIdx.x;
  if (b >= B_) return;
  float P[C_];
#pragma unroll
  for (int c = 0; c < C_; ++c) {
    float s = 0.f;
#pragma unroll
    for (int u = 0; u < 8; ++u) s += pooled[(b * C_ + c) * 8 + u];
    P[c] = s;
  }
  float qd[4];
#pragma unroll
  for (int i = 0; i < 4; ++i) {
    float s = bq[i];
#pragma unroll
    for (int c = 0; c < C_; ++c) s = fmaf(P[c], wq[i * C_ + c], s);
    qd[i] = s;
  }
  float td[3];
#pragma unroll
  for (int i = 0; i < 3; ++i) {
    float s = bt[i];
#pragma unroll
    for (int c = 0; c < C_; ++c) s = fmaf(P[c], wt[i * C_ + c], s);
    td[i] = s;
  }
  float nq = sqrtf(qd[0] * qd[0] + qd[1] * qd[1] + qd[2] * qd[2] + qd[3] * qd[3]) + 1e-10f;
#pragma unroll
  for (int i = 0; i < 4; ++i) qd[i] /= nq;
  float cw = qc[b * 4 + 0], cx = qc[b * 4 + 1], cyy = qc[b * 4 + 2], cz = qc[b * 4 + 3];
  float qnw = qd[0] * cw - qd[1] * cx - qd[2] * cyy - qd[3] * cz;
  float qnx = qd[0] * cx + qd[1] * cw + qd[2] * cz - qd[3] * cyy;
  float qny = qd[0] * cyy - qd[1] * cz + qd[2] * cw + qd[3] * cx;
  float qnz = qd[0] * cz + qd[1] * cyy - qd[2] * cx + qd[3] * cw;
  float nn = sqrtf(qnw * qnw + qnx * qnx + qny * qny + qnz * qnz) + 1e-10f;
  float vx = tc[b * 3 + 0], vy = tc[b * 3 + 1], vz = tc[b * 3 + 2];
  float aw = -(qd[1] * vx + qd[2] * vy + qd[3] * vz);
  float ax = qd[0] * vx + qd[2] * vz - qd[3] * vy;
  float ay = qd[0] * vy - qd[1] * vz + qd[3] * vx;
  float az = qd[0] * vz + qd[1] * vy - qd[2] * vx;
  float n2 = qd[0] * qd[0] + qd[1] * qd[1] + qd[2] * qd[2] + qd[3] * qd[3] + 1e-10f;
  float bw = qd[0] / n2, bx = -qd[1] / n2, by = -qd[2] / n2, bz = -qd[3] / n2;
  float rx = aw * bx + ax * bw + ay * bz - az * by;
  float ry = aw * by - ax * bz + ay * bw + az * bx;
  float rz = aw * bz + ax * by - ay * bx + az * bw;
  out[b * 7 + 0] = qnw / nn;
  out[b * 7 + 1] = qnx / nn;
  out[b * 7 + 2] = qny / nn;
  out[b * 7 + 3] = qnz / nn;
  out[b * 7 + 4] = rx + td[0];
  out[b * 7 + 5] = ry + td[1];
  out[b * 7 + 6] = rz + td[2];
}

extern "C" void kernel_launch(void* const* d_in, const int* in_sizes, int n_in,
                              void* d_out, int out_size, void* d_ws, size_t ws_size,
                              hipStream_t stream) {
  const float* pos1 = (const float*)d_in[0];
  const float* pos2 = (const float*)d_in[1];
  const float* feat1 = (const float*)d_in[2];
  const float* feat2 = (const float*)d_in[3];
  const float* qc = (const float*)d_in[4];
  const float* tc = (const float*)d_in[5];
  const float* w1_0 = (const float*)d_in[6];
  const float* g1_0 = (const float*)d_in[7];
  const float* b1_0 = (const float*)d_in[8];
  const float* w1_1 = (const float*)d_in[9];
  const float* g1_1 = (const float*)d_in[10];
  const float* b1_1 = (const float*)d_in[11];
  const float* w1_2 = (const float*)d_in[12];
  const float* g1_2 = (const float*)d_in[13];
  const float* b1_2 = (const float*)d_in[14];
  const float* w2_0 = (const float*)d_in[15];
  const float* g2_0 = (const float*)d_in[16];
  const float* b2_0 = (const float*)d_in[17];
  const float* w2_1 = (const float*)d_in[18];
  const float* g2_1 = (const float*)d_in[19];
  const float* b2_1 = (const float*)d_in[20];
  const float* wq = (const float*)d_in[21];
  const float* bq = (const float*)d_in[22];
  const float* wt = (const float*)d_in[23];
  const float* bt = (const float*)d_in[24];

  float* ws = (float*)d_ws;
  const size_t off_stat = 0;          // 8192
  const size_t off_pool = 8192;       // 2048
  const size_t off_wb = 10240;        // 26624
  const size_t off_pts4w = 36864;     // 65536
  const size_t off_pts4p = 102400;    // 65536
  const size_t off_pairW = 167936;    // 65536
  const size_t off_pairP = 233472;    // 65536
  const size_t off_knnK = 299008;     // 1572864 ints
  const size_t off_idxM1 = 1871872;   // 98304 ints
  const size_t off_idxM2 = 1970176;   // 65536 ints
  const size_t off_P2a = 2035712;     // 1048576 (bf16 16384x128)
  const size_t off_P1a = 3084288;     // 1048576
  const size_t off_P1b = 4132864;     // 1048576
  const size_t off_Pfe = 5181440;     // 1048576
  const size_t off_yA = 6230016;      // 3145728 (98304x64 bf16)
  const size_t off_yB = 9375744;      // 3145728

  float* stat0 = ws + off_stat;  // 128*16
  float* stat1 = stat0 + 2048;   // 64*16
  float* stat2 = stat1 + 1024;   // 64*16
  float* stat3 = stat2 + 1024;   // 128*16
  float* stat4 = stat3 + 2048;   // 64*16
  float* pooled = ws + off_pool;
  unsigned short* Wf2a = (unsigned short*)(ws + off_wb);  // 128x64
  unsigned short* Wf1a = Wf2a + 8192;                     // 128x64
  unsigned short* Wfe = Wf1a + 8192;                      // 128x64
  unsigned short* Wf1b = Wfe + 8192;                      // 128x64
  unsigned short* wb1 = Wf1b + 8192;                      // 64x128
  unsigned short* wb2 = wb1 + 8192;                       // 64x64
  unsigned short* wb4 = wb2 + 4096;                       // 64x128
  float4* pts4w = (float4*)(ws + off_pts4w);
  float4* pts4p = (float4*)(ws + off_pts4p);
  float4* pairW = (float4*)(ws + off_pairW);
  float4* pairP = (float4*)(ws + off_pairP);
  int* knnK = (int*)(ws + off_knnK);
  int* idxM1 = (int*)(ws + off_idxM1);
  int* idxM2 = (int*)(ws + off_idxM2);
  unsigned short* P2a = (unsigned short*)(ws + off_P2a);
  unsigned short* P1a = (unsigned short*)(ws + off_P1a);
  unsigned short* P1b = (unsigned short*)(ws + off_P1b);
  unsigned short* Pfe = (unsigned short*)(ws + off_Pfe);
  unsigned short* yA = (unsigned short*)(ws + off_yA);
  unsigned short* yB = (unsigned short*)(ws + off_yB);

  k_init<<<dim3(64, 9), 256, 0, stream>>>(w1_0, w1_1, w1_2, w2_0, w2_1, Wf2a, Wf1a,
                                          Wfe, Wf1b, wb1, wb2, wb4, pos1, pos2, qc, tc,
                                          pts4w, pts4p, pairW, pairP, ws + off_stat);

  k_knnproj<<<dim3(768 + 1024), 256, 0, stream>>>(pts4w, pairW, pairP, knnK, feat2,
                                                  Wf2a, P2a, feat1, Wf1a, P1a, Wf1b,
                                                  P1b);

  // MLP1: stat-only pass over y0, then fused gather-GEMM
  k_stat0<K2_><<<dim3(98304 / 128), 256, 0, stream>>>(w1_0, pts4p, pts4w, P2a, P1a,
                                                      knnK, idxM1, stat0);
  k_layerG<K2_><<<dim3(98304 / 64), 256, 0, stream>>>(
      wb1, w1_0, pts4p, pts4w, P2a, P1a, idxM1, stat0, g1_0, b1_0, 1.f / 98304.f, yA,
      stat1);
  // MLP1 L2: 64->64
  k_layer64<<<dim3(98304 / 64), 256, 0, stream>>>(wb2, yA, stat1, g1_1, b1_1,
                                                  1.f / 98304.f, yB, stat2);
  // fused fe + Pfe projection
  k_feproj<<<dim3(256), 256, 0, stream>>>(yB, stat2, g1_2, b1_2, Wfe, Pfe);
  // MLP2: stat-only pass then fused gather-GEMM
  k_stat0<K1_><<<dim3(65536 / 128), 256, 0, stream>>>(
      w2_0, pts4w, pts4w, Pfe, P1b, knnK + (size_t)BN_ * NCH_ * 6, idxM2, stat3);
  k_layerG<K1_><<<dim3(65536 / 64), 256, 0, stream>>>(
      wb4, w2_0, pts4w, pts4w, Pfe, P1b, idxM2, stat3, g2_0, b2_0, 1.f / 65536.f, yA,
      stat4);
  // pooled
  k_pooled<<<dim3(65536 / 64), 256, 0, stream>>>(yA, stat4, g2_1, b2_1, pooled);
  // head
  k_final<<<dim3(1), 64, 0, stream>>>(pooled, wq, bq, wt, bt, qc, tc, (float*)d_out);
}

// Round 17
// 355.314 us; speedup vs baseline: 1.0252x; 1.0252x over previous
//
#include <hip/hip_runtime.h>
#include <math.h>

#define B_ 4
#define N_ 4096
#define C_ 64
#define K1_ 4
#define K2_ 6
#define EPS_ 1e-5f
#define BN_ (B_ * N_)
#define NCH_ 8
#define CHP_ 512
#define STKD_ 16

typedef __attribute__((ext_vector_type(8))) short bf16x8;
typedef __attribute__((ext_vector_type(4))) float f32x4;
typedef __attribute__((ext_vector_type(2))) float f32x2;

__device__ __forceinline__ unsigned short f2bf(float f) {
  unsigned int u = __float_as_uint(f);
  unsigned int r = (u + 0x7fffu + ((u >> 16) & 1u)) >> 16;
  return (unsigned short)r;
}
__device__ __forceinline__ float bf2f(unsigned short u) {
  return __uint_as_float(((unsigned int)u) << 16);
}
__device__ __forceinline__ void unpack8(uint4 u, float* f) {
  unsigned* up = (unsigned*)&u;
#pragma unroll
  for (int w = 0; w < 4; ++w) {
    f[2 * w] = __uint_as_float(up[w] << 16);
    f[2 * w + 1] = __uint_as_float(up[w] & 0xFFFF0000u);
  }
}

template <int K>
__device__ __forceinline__ void insKi(int* kd, int k) {
  int x = k;
#pragma unroll
  for (int u = 0; u < K; ++u) {
    int lo = min(kd[u], x);
    x = max(kd[u], x);
    kd[u] = lo;
  }
}

// ---------------- init: weight conversion + pose/tables + zeroing --------------
__global__ __launch_bounds__(256) void k_init(
    const float* __restrict__ w1_0, const float* __restrict__ w1_1,
    const float* __restrict__ w1_2, const float* __restrict__ w2_0,
    const float* __restrict__ w2_1, unsigned short* __restrict__ Wf2a,
    unsigned short* __restrict__ Wf1a, unsigned short* __restrict__ Wfe,
    unsigned short* __restrict__ Wf1b, unsigned short* __restrict__ wb1,
    unsigned short* __restrict__ wb2, unsigned short* __restrict__ wb4,
    const float* __restrict__ pos1, const float* __restrict__ pos2,
    const float* __restrict__ qc, const float* __restrict__ tc,
    float4* __restrict__ pts4w, float4* __restrict__ pts4p,
    float4* __restrict__ pairW, float4* __restrict__ pairP,
    float* __restrict__ zbase) {
  int t = blockIdx.x * 256 + threadIdx.x;
  int m = blockIdx.y;
  if (m < 7) {
    switch (m) {
      case 0:
        if (t < 8192) Wf2a[t] = f2bf(w1_0[(t >> 6) * 131 + 3 + (t & 63)]);
        break;
      case 1:
        if (t < 8192) Wf1a[t] = f2bf(w1_0[(t >> 6) * 131 + 67 + (t & 63)]);
        break;
      case 2:
        if (t < 8192) Wfe[t] = f2bf(w2_0[(t >> 6) * 131 + 3 + (t & 63)]);
        break;
      case 3:
        if (t < 8192) Wf1b[t] = f2bf(w2_0[(t >> 6) * 131 + 67 + (t & 63)]);
        break;
      case 4:
        if (t < 8192) wb1[t] = f2bf(w1_1[t]);
        break;
      case 5:
        if (t < 4096) wb2[t] = f2bf(w1_2[t]);
        break;
      default:
        if (t < 8192) wb4[t] = f2bf(w2_1[t]);
        break;
    }
    return;
  }
  if (m == 8) {
    if (t < 10240) zbase[t] = 0.f;  // stat(8192) + pooled(2048)
    return;
  }
  if (t >= BN_) return;
  int b = t / N_;
  float qw = qc[b * 4 + 0], qx = qc[b * 4 + 1], qy = qc[b * 4 + 2], qz = qc[b * 4 + 3];
  float vx = pos1[t * 3 + 0], vy = pos1[t * 3 + 1], vz = pos1[t * 3 + 2];
  float aw = -(qx * vx + qy * vy + qz * vz);
  float ax = qw * vx + qy * vz - qz * vy;
  float ay = qw * vy - qx * vz + qz * vx;
  float az = qw * vz + qx * vy - qy * vx;
  float n2 = qw * qw + qx * qx + qy * qy + qz * qz + 1e-10f;
  float bw = qw / n2, bx = -qx / n2, by = -qy / n2, bz = -qz / n2;
  float rx = aw * bx + ax * bw + ay * bz - az * by;
  float ry = aw * by - ax * bz + ay * bw + az * bx;
  float rz = aw * bz + ax * by - ay * bx + az * bw;
  rx += tc[b * 3 + 0];
  ry += tc[b * 3 + 1];
  rz += tc[b * 3 + 2];
  float rw2 = rx * rx + ry * ry + rz * rz;
  pts4w[t] = make_float4(rx, ry, rz, rw2);
  int p = t >> 1, h = t & 1;
  float* bwp = (float*)&pairW[(size_t)2 * p];
  bwp[0 + h] = rx; bwp[2 + h] = ry; bwp[4 + h] = rz; bwp[6 + h] = rw2;
  float px = pos2[t * 3 + 0], py = pos2[t * 3 + 1], pz = pos2[t * 3 + 2];
  float pw2 = px * px + py * py + pz * pz;
  pts4p[t] = make_float4(px, py, pz, pw2);
  float* bpp = (float*)&pairP[(size_t)2 * p];
  bpp[0 + h] = px; bpp[2 + h] = py; bpp[4 + h] = pz; bpp[6 + h] = pw2;
}

// ---------------- shared MFMA 64x128x64 tail (bf16 output) ---------------------
__device__ __forceinline__ void proj_mfma_tail(const unsigned short* Xs, int tid,
                                               int row0,
                                               const unsigned short* __restrict__ Wb,
                                               unsigned short* __restrict__ dst) {
  constexpr int SP = 72;
  int l = tid & 63, wv = tid >> 6;
  int lm = l & 15, quad = l >> 4;
  int n0 = wv * 32;
  f32x4 acc[4][2];
#pragma unroll
  for (int rt = 0; rt < 4; ++rt)
#pragma unroll
    for (int ct = 0; ct < 2; ++ct) acc[rt][ct] = (f32x4)(0.f);
#pragma unroll
  for (int k0 = 0; k0 < 64; k0 += 32) {
    bf16x8 a[4], b[2];
#pragma unroll
    for (int rt = 0; rt < 4; ++rt)
      a[rt] = *(const bf16x8*)&Xs[(rt * 16 + lm) * SP + k0 + quad * 8];
#pragma unroll
    for (int ct = 0; ct < 2; ++ct)
      b[ct] = *(const bf16x8*)&Wb[(size_t)(n0 + ct * 16 + lm) * 64 + k0 + quad * 8];
#pragma unroll
    for (int rt = 0; rt < 4; ++rt)
#pragma unroll
      for (int ct = 0; ct < 2; ++ct)
        acc[rt][ct] =
            __builtin_amdgcn_mfma_f32_16x16x32_bf16(a[rt], b[ct], acc[rt][ct], 0, 0, 0);
  }
#pragma unroll
  for (int rt = 0; rt < 4; ++rt)
#pragma unroll
    for (int ct = 0; ct < 2; ++ct)
#pragma unroll
      for (int r = 0; r < 4; ++r) {
        int row = row0 + rt * 16 + quad * 4 + r;
        dst[(size_t)row * 128 + n0 + ct * 16 + lm] = f2bf(acc[rt][ct][r]);
      }
}

// ---------------- KNN chunk body (LDS stack + ballot drain — best measured) ----
// R16 lesson: unconditional bubble insert regressed (12-op dependent chain paid
// per pair). Stack batches the chain cost onto accepted candidates only.
template <int K>
__device__ __forceinline__ void knn_chunk(const f32x4* __restrict__ PT, int base,
                                          float4 qv, int tid, int (*st)[256],
                                          int* __restrict__ orow) {
  f32x2 qq2 = (f32x2)(qv.w);
  f32x2 m2x = (f32x2)(-2.f * qv.x);
  f32x2 m2y = (f32x2)(-2.f * qv.y);
  f32x2 m2z = (f32x2)(-2.f * qv.z);
  int kd[K];
#pragma unroll
  for (int t = 0; t < K; ++t) kd[t] = 0x7fffffff;
  int kbd = 0x7fffffff;
  int ptr = 0;
  for (int jj = 0; jj < CHP_; jj += 8) {
    f32x2 d[4];
#pragma unroll
    for (int gq = 0; gq < 2; ++gq) {
      f32x4 e0 = PT[jj + gq * 4 + 0];
      f32x4 e1 = PT[jj + gq * 4 + 1];
      f32x4 e2 = PT[jj + gq * 4 + 2];
      f32x4 e3 = PT[jj + gq * 4 + 3];
      d[gq * 2 + 0] = __builtin_elementwise_fma(
          m2x, e0.xy,
          __builtin_elementwise_fma(m2y, e0.zw,
                                    __builtin_elementwise_fma(m2z, e1.xy, e1.zw + qq2)));
      d[gq * 2 + 1] = __builtin_elementwise_fma(
          m2x, e2.xy,
          __builtin_elementwise_fma(m2y, e2.zw,
                                    __builtin_elementwise_fma(m2z, e3.xy, e3.zw + qq2)));
    }
    int j0 = base + jj;
#pragma unroll
    for (int p = 0; p < 4; ++p) {
      int ka = (int)((__float_as_uint(d[p].x) & 0xFFFFF000u) | (unsigned)(j0 + 2 * p));
      int kb = (int)((__float_as_uint(d[p].y) & 0xFFFFF000u) | (unsigned)(j0 + 2 * p + 1));
      st[ptr][tid] = ka;
      ptr += (ka < kbd) ? 1 : 0;
      st[ptr][tid] = kb;
      ptr += (kb < kbd) ? 1 : 0;
    }
    if (__ballot(ptr >= STKD_ - 8)) {
      for (int i = 0; i < ptr; ++i) insKi<K>(kd, st[i][tid]);
      ptr = 0;
      kbd = kd[K - 1];
    }
  }
  for (int i = 0; i < ptr; ++i) insKi<K>(kd, st[i][tid]);
#pragma unroll
  for (int t = 0; t < K; ++t) orow[t] = kd[t];
}

// ---------------- fused: 3x proj GEMM + dual-KNN -------------------------------
__global__ __launch_bounds__(256) void k_knnproj(
    const float4* __restrict__ pts4w, const float4* __restrict__ pairW,
    const float4* __restrict__ pairP, int* __restrict__ outK,
    const float* __restrict__ feat2, const unsigned short* __restrict__ Wf2a,
    unsigned short* __restrict__ P2a, const float* __restrict__ feat1,
    const unsigned short* __restrict__ Wf1a, unsigned short* __restrict__ P1a,
    const unsigned short* __restrict__ Wf1b, unsigned short* __restrict__ P1b) {
  __shared__ int st[STKD_][256];
  int tid = threadIdx.x;
  int bid = blockIdx.x;
  if (bid < 768) {
    const float* src;
    const unsigned short* Wb;
    unsigned short* dst;
    switch (bid >> 8) {
      case 0: src = feat2; Wb = Wf2a; dst = P2a; break;
      case 1: src = feat1; Wb = Wf1a; dst = P1a; break;
      default: src = feat1; Wb = Wf1b; dst = P1b; break;
    }
    unsigned short* Xs = (unsigned short*)&st[0][0];  // 9216 B <= 16384 B
    int row0 = (bid & 255) * 64;
    for (int e = tid; e < 64 * 16; e += 256) {
      int r = e >> 4, s = e & 15;
      float4 v = *(const float4*)&src[(size_t)(row0 + r) * 64 + s * 4];
      ushort4 o;
      o.x = f2bf(v.x); o.y = f2bf(v.y); o.z = f2bf(v.z); o.w = f2bf(v.w);
      *(ushort4*)&Xs[r * 72 + s * 4] = o;
    }
    __syncthreads();
    proj_mfma_tail(Xs, tid, row0, Wb, dst);
    return;
  }
  int kbid = bid - 768;
  int x = kbid & 15, y = (kbid >> 4) & 7, z = kbid >> 7;
  int b = z & 3;
  int which = z >> 2;
  const f32x4* __restrict__ PT =
      (const f32x4*)((which ? pairW : pairP) + (size_t)b * N_ + y * CHP_);
  int base = y * CHP_;
  int n = x * 256 + tid;
  float4 qv = pts4w[(size_t)b * N_ + n];
  int* orow = &outK[((size_t)which * BN_ * NCH_ + (size_t)(b * N_ + n) * NCH_ + y) * 6];
  if (which == 0)
    knn_chunk<6>(PT, base, qv, tid, st, orow);
  else
    knn_chunk<4>(PT, base, qv, tid, st, orow);
}

// ---------------- fused fe + projection ----------------------------------------
__global__ __launch_bounds__(256) void k_feproj(const unsigned short* __restrict__ y3,
                                                const float* __restrict__ stat,
                                                const float* __restrict__ g,
                                                const float* __restrict__ bb,
                                                const unsigned short* __restrict__ Wfe,
                                                unsigned short* __restrict__ Pfe) {
  constexpr int SP = 72;
  __shared__ unsigned short Xs[64 * SP];
  __shared__ float scl[C_], shf[C_];
  int tid = threadIdx.x;
  if (tid < C_) {
    int c = tid;
    float s = 0.f, s2 = 0.f;
#pragma unroll
    for (int u = 0; u < 8; ++u) {
      s += stat[c * 8 + u];
      s2 += stat[C_ * 8 + c * 8 + u];
    }
    const float invM = 1.f / (float)(BN_ * K2_);
    float m = s * invM;
    float v = s2 * invM - m * m;
    float sc = g[c] * rsqrtf(v + EPS_);
    scl[c] = sc;
    shf[c] = bb[c] - m * sc;
  }
  __syncthreads();
  int row0 = blockIdx.x * 64;
  for (int e = tid; e < 64 * 16; e += 256) {
    int r = e >> 4, s = e & 15;
    size_t base = ((size_t)(row0 + r) * K2_) * C_ + s * 4;
    float a0 = 0.f, a1 = 0.f, a2 = 0.f, a3 = 0.f;
#pragma unroll
    for (int k = 0; k < K2_; ++k) {
      ushort4 u = *(const ushort4*)&y3[base + (size_t)k * C_];
      a0 += fmaxf(fmaf(bf2f(u.x), scl[s * 4 + 0], shf[s * 4 + 0]), 0.f);
      a1 += fmaxf(fmaf(bf2f(u.y), scl[s * 4 + 1], shf[s * 4 + 1]), 0.f);
      a2 += fmaxf(fmaf(bf2f(u.z), scl[s * 4 + 2], shf[s * 4 + 2]), 0.f);
      a3 += fmaxf(fmaf(bf2f(u.w), scl[s * 4 + 3], shf[s * 4 + 3]), 0.f);
    }
    ushort4 o;
    o.x = f2bf(a0); o.y = f2bf(a1); o.z = f2bf(a2); o.w = f2bf(a3);
    *(ushort4*)&Xs[r * SP + s * 4] = o;
  }
  __syncthreads();
  proj_mfma_tail(Xs, tid, row0, Wfe, Pfe);
}

// ---------------- stat0: merge knnK -> idxM (gj) + BN stats of y0 --------------
template <int KNN>
__global__ __launch_bounds__(256) void k_stat0(
    const float* __restrict__ Wfull, const float4* __restrict__ nbrPts,
    const float4* __restrict__ qryPts, const unsigned short* __restrict__ Pj,
    const unsigned short* __restrict__ Pn, const int* __restrict__ outK,
    int* __restrict__ idxM, float* __restrict__ statOut) {
  __shared__ float Wx[3][128];
  __shared__ float red[16][128];
  __shared__ int idxL[33][6];
  int tid = threadIdx.x;
  int row0 = blockIdx.x * 128;
  int first = row0 / KNN;
  int nq = (row0 + 127) / KNN - first + 1;
  if (tid < 128) {
    Wx[0][tid] = Wfull[tid * 131 + 0];
    Wx[1][tid] = Wfull[tid * 131 + 1];
    Wx[2][tid] = Wfull[tid * 131 + 2];
  }
  if (tid < nq) {
    int q = first + tid;
    int km[6];
#pragma unroll
    for (int u = 0; u < 6; ++u) km[u] = 0x7fffffff;
    size_t ib = (size_t)q * (NCH_ * 6);
    if (KNN == 6) {
      for (int c = 0; c < NCH_ * 6; ++c) insKi<6>(km, outK[ib + c]);
    } else {
      for (int ch = 0; ch < NCH_; ++ch)
#pragma unroll
        for (int u = 0; u < 4; ++u) insKi<4>(km, outK[ib + ch * 6 + u]);
    }
    int bb = (q >> 12) << 12;
#pragma unroll
    for (int u = 0; u < KNN; ++u) {
      int gj = bb + (km[u] & 0xFFF);
      idxL[tid][u] = gj;
      idxM[(size_t)q * KNN + u] = gj;
    }
  }
  __syncthreads();
  int cg = tid & 15, rg = tid >> 4;
  int c0 = cg * 8;
  float wx0[8], wx1[8], wx2[8];
#pragma unroll
  for (int u = 0; u < 8; ++u) {
    wx0[u] = Wx[0][c0 + u];
    wx1[u] = Wx[1][c0 + u];
    wx2[u] = Wx[2][c0 + u];
  }
  float s1[8], s2[8];
#pragma unroll
  for (int u = 0; u < 8; ++u) { s1[u] = 0.f; s2[u] = 0.f; }
#pragma unroll
  for (int i = 0; i < 8; ++i) {
    int row = row0 + rg * 8 + i;
    int g = row / KNN;
    int gj = idxL[g - first][row - g * KNN];
    float4 pw = qryPts[g];
    float4 pn4 = nbrPts[gj];
    float xd0 = pn4.x - pw.x;
    float xd1 = pn4.y - pw.y;
    float xd2 = pn4.z - pw.z;
    uint4 uj = *(const uint4*)&Pj[(size_t)gj * 128 + c0];
    uint4 un = *(const uint4*)&Pn[(size_t)g * 128 + c0];
    float yj[8], yn[8];
    unpack8(uj, yj);
    unpack8(un, yn);
#pragma unroll
    for (int u = 0; u < 8; ++u) {
      float v = yj[u] + yn[u];
      v = fmaf(xd0, wx0[u], v);
      v = fmaf(xd1, wx1[u], v);
      v = fmaf(xd2, wx2[u], v);
      s1[u] += v;
      s2[u] = fmaf(v, v, s2[u]);
    }
  }
  int slot = blockIdx.x & 7;
#pragma unroll
  for (int u = 0; u < 8; ++u) red[rg][c0 + u] = s1[u];
  __syncthreads();
  if (tid < 128) {
    float s = 0.f;
#pragma unroll
    for (int r = 0; r < 16; ++r) s += red[r][tid];
    atomicAdd(&statOut[tid * 8 + slot], s);
  }
  __syncthreads();
#pragma unroll
  for (int u = 0; u < 8; ++u) red[rg][c0 + u] = s2[u];
  __syncthreads();
  if (tid < 128) {
    float s = 0.f;
#pragma unroll
    for (int r = 0; r < 16; ++r) s += red[r][tid];
    atomicAdd(&statOut[128 * 8 + tid * 8 + slot], s);
  }
}

// ---------------- layerG: recompute y0 from P + bn/relu -> MFMA (128->64) ------
template <int KNN>
__global__ __launch_bounds__(256) void k_layerG(
    const unsigned short* __restrict__ Wb,  // [64][128] bf16
    const float* __restrict__ Wfull, const float4* __restrict__ nbrPts,
    const float4* __restrict__ qryPts, const unsigned short* __restrict__ Pj,
    const unsigned short* __restrict__ Pn, const int* __restrict__ idxM,
    const float* __restrict__ statPrev, const float* __restrict__ gPrev,
    const float* __restrict__ bPrev, float prevInvM,
    unsigned short* __restrict__ yout,  // [rows][64] bf16
    float* __restrict__ statOut) {
  constexpr int KP = 128, COUT = 64;
  constexpr int SP = KP + 8;
  constexpr int CST = COUT + 8;
  __shared__ unsigned short Xs[64 * SP];
  __shared__ float scl[KP];
  __shared__ float shf[KP];
  __shared__ float Wx[3][128];
  __shared__ int gjL[64];
  __shared__ float xdL[3][64];

  int tid = threadIdx.x;
  int row0 = blockIdx.x * 64;

  for (int c = tid; c < KP; c += 256) {
    float s = 0.f, s2 = 0.f;
#pragma unroll
    for (int u = 0; u < 8; ++u) {
      s += statPrev[c * 8 + u];
      s2 += statPrev[KP * 8 + c * 8 + u];
    }
    float m = s * prevInvM;
    float v = s2 * prevInvM - m * m;
    float sc = gPrev[c] * rsqrtf(v + EPS_);
    scl[c] = sc;
    shf[c] = bPrev[c] - m * sc;
  }
  if (tid < 128) {
    Wx[0][tid] = Wfull[tid * 131 + 0];
    Wx[1][tid] = Wfull[tid * 131 + 1];
    Wx[2][tid] = Wfull[tid * 131 + 2];
  }
  if (tid < 64) {
    int row = row0 + tid;
    int g = row / KNN;
    int gj = idxM[(size_t)g * KNN + (row - g * KNN)];
    gjL[tid] = gj;
    float4 pw = qryPts[g];
    float4 pn4 = nbrPts[gj];
    xdL[0][tid] = pn4.x - pw.x;
    xdL[1][tid] = pn4.y - pw.y;
    xdL[2][tid] = pn4.z - pw.z;
  }
  __syncthreads();
  for (int e = tid; e < 64 * 16; e += 256) {
    int r = e >> 4, s = e & 15;
    int c0 = s * 8;
    int row = row0 + r;
    int g = row / KNN;
    uint4 uj = *(const uint4*)&Pj[(size_t)gjL[r] * 128 + c0];
    uint4 un = *(const uint4*)&Pn[(size_t)g * 128 + c0];
    float yj[8], yn[8];
    unpack8(uj, yj);
    unpack8(un, yn);
    float xd0 = xdL[0][r], xd1 = xdL[1][r], xd2 = xdL[2][r];
    unsigned short ob[8];
#pragma unroll
    for (int u = 0; u < 8; ++u) {
      int c = c0 + u;
      float v = yj[u] + yn[u];
      v = fmaf(xd0, Wx[0][c], v);
      v = fmaf(xd1, Wx[1][c], v);
      v = fmaf(xd2, Wx[2][c], v);
      ob[u] = f2bf(fmaxf(fmaf(v, scl[c], shf[c]), 0.f));
    }
    ushort4 o0, o1;
    o0.x = ob[0]; o0.y = ob[1]; o0.z = ob[2]; o0.w = ob[3];
    o1.x = ob[4]; o1.y = ob[5]; o1.z = ob[6]; o1.w = ob[7];
    *(ushort4*)&Xs[r * SP + c0] = o0;
    *(ushort4*)&Xs[r * SP + c0 + 4] = o1;
  }
  __syncthreads();

  int l = tid & 63, wv = tid >> 6;
  int lm = l & 15, quad = l >> 4;
  int n0 = wv * 16;

  f32x4 acc[4];
#pragma unroll
  for (int rt = 0; rt < 4; ++rt) acc[rt] = (f32x4)(0.f);

#pragma unroll
  for (int k0 = 0; k0 < KP; k0 += 32) {
    bf16x8 b = *(const bf16x8*)&Wb[(size_t)(n0 + lm) * KP + k0 + quad * 8];
#pragma unroll
    for (int rt = 0; rt < 4; ++rt) {
      bf16x8 a = *(const bf16x8*)&Xs[(rt * 16 + lm) * SP + k0 + quad * 8];
      acc[rt] = __builtin_amdgcn_mfma_f32_16x16x32_bf16(a, b, acc[rt], 0, 0, 0);
    }
  }

  int slot = blockIdx.x & 7;
  {
    float s1 = 0.f, s2 = 0.f;
#pragma unroll
    for (int rt = 0; rt < 4; ++rt)
#pragma unroll
      for (int r = 0; r < 4; ++r) {
        float v = acc[rt][r];
        s1 += v;
        s2 += v * v;
      }
    s1 += __shfl_xor(s1, 16);
    s1 += __shfl_xor(s1, 32);
    s2 += __shfl_xor(s2, 16);
    s2 += __shfl_xor(s2, 32);
    if (quad == 0) {
      int col = n0 + lm;
      atomicAdd(&statOut[col * 8 + slot], s1);
      atomicAdd(&statOut[COUT * 8 + col * 8 + slot], s2);
    }
  }

  __syncthreads();
  unsigned short* Ys = Xs;
#pragma unroll
  for (int rt = 0; rt < 4; ++rt)
#pragma unroll
    for (int r = 0; r < 4; ++r)
      Ys[(rt * 16 + quad * 4 + r) * CST + n0 + lm] = f2bf(acc[rt][r]);
  __syncthreads();
  for (int e = tid; e < 64 * 8; e += 256) {
    int r = e >> 3, c0 = (e & 7) * 8;
    uint4 v = *(const uint4*)&Ys[r * CST + c0];
    *(uint4*)&yout[((size_t)(row0 + r)) * COUT + c0] = v;
  }
}

// ---------------- PLAIN BN-relu + MFMA layer (64->64) --------------------------
__global__ __launch_bounds__(256) void k_layer64(
    const unsigned short* __restrict__ Wb,     // [64][64] bf16
    const unsigned short* __restrict__ yprev,  // [rows][64] bf16
    const float* __restrict__ statPrev, const float* __restrict__ gPrev,
    const float* __restrict__ bPrev, float prevInvM,
    unsigned short* __restrict__ yout, float* __restrict__ statOut) {
  constexpr int KP = 64, COUT = 64;
  constexpr int SP = KP + 8;
  constexpr int CST = COUT + 8;
  __shared__ unsigned short Xs[64 * SP];
  __shared__ float scl[KP];
  __shared__ float shf[KP];

  int tid = threadIdx.x;
  int row0 = blockIdx.x * 64;

  for (int c = tid; c < KP; c += 256) {
    float s = 0.f, s2 = 0.f;
#pragma unroll
    for (int u = 0; u < 8; ++u) {
      s += statPrev[c * 8 + u];
      s2 += statPrev[KP * 8 + c * 8 + u];
    }
    float m = s * prevInvM;
    float v = s2 * prevInvM - m * m;
    float sc = gPrev[c] * rsqrtf(v + EPS_);
    scl[c] = sc;
    shf[c] = bPrev[c] - m * sc;
  }
  __syncthreads();
  for (int e = tid; e < 64 * 8; e += 256) {
    int r = e >> 3, s = e & 7;
    int row = row0 + r;
    uint4 u = *(const uint4*)&yprev[(size_t)row * KP + s * 8];
    uint4 o;
    unsigned* up = (unsigned*)&u;
    unsigned* op = (unsigned*)&o;
#pragma unroll
    for (int w = 0; w < 4; ++w) {
      int c = s * 8 + w * 2;
      float lo = __uint_as_float(up[w] << 16);
      float hi = __uint_as_float(up[w] & 0xFFFF0000u);
      float rl = fmaxf(fmaf(lo, scl[c], shf[c]), 0.f);
      float rh = fmaxf(fmaf(hi, scl[c + 1], shf[c + 1]), 0.f);
      op[w] = (unsigned)f2bf(rl) | ((unsigned)f2bf(rh) << 16);
    }
    *(uint4*)&Xs[r * SP + s * 8] = o;
  }
  __syncthreads();

  int l = tid & 63, wv = tid >> 6;
  int lm = l & 15, quad = l >> 4;
  int n0 = wv * 16;

  f32x4 acc[4];
#pragma unroll
  for (int rt = 0; rt < 4; ++rt) acc[rt] = (f32x4)(0.f);
#pragma unroll
  for (int k0 = 0; k0 < KP; k0 += 32) {
    bf16x8 b = *(const bf16x8*)&Wb[(size_t)(n0 + lm) * KP + k0 + quad * 8];
#pragma unroll
    for (int rt = 0; rt < 4; ++rt) {
      bf16x8 a = *(const bf16x8*)&Xs[(rt * 16 + lm) * SP + k0 + quad * 8];
      acc[rt] = __builtin_amdgcn_mfma_f32_16x16x32_bf16(a, b, acc[rt], 0, 0, 0);
    }
  }

  int slot = blockIdx.x & 7;
  {
    float s1 = 0.f, s2 = 0.f;
#pragma unroll
    for (int rt = 0; rt < 4; ++rt)
#pragma unroll
      for (int r = 0; r < 4; ++r) {
        float v = acc[rt][r];
        s1 += v;
        s2 += v * v;
      }
    s1 += __shfl_xor(s1, 16);
    s1 += __shfl_xor(s1, 32);
    s2 += __shfl_xor(s2, 16);
    s2 += __shfl_xor(s2, 32);
    if (quad == 0) {
      int col = n0 + lm;
      atomicAdd(&statOut[col * 8 + slot], s1);
      atomicAdd(&statOut[COUT * 8 + col * 8 + slot], s2);
    }
  }

  __syncthreads();
  unsigned short* Ys = Xs;
#pragma unroll
  for (int rt = 0; rt < 4; ++rt)
#pragma unroll
    for (int r = 0; r < 4; ++r)
      Ys[(rt * 16 + quad * 4 + r) * CST + n0 + lm] = f2bf(acc[rt][r]);
  __syncthreads();
  for (int e = tid; e < 64 * 8; e += 256) {
    int r = e >> 3, c0 = (e & 7) * 8;
    uint4 v = *(const uint4*)&Ys[r * CST + c0];
    *(uint4*)&yout[((size_t)(row0 + r)) * COUT + c0] = v;
  }
}

// ---------------- pooled[b][c] = sum_{n,k} relu(bn(y5)) ------------------------
__global__ __launch_bounds__(256) void k_pooled(const unsigned short* __restrict__ y5,
                                                const float* __restrict__ stat,
                                                const float* __restrict__ g,
                                                const float* __restrict__ bb,
                                                float* __restrict__ pooled) {
  __shared__ float scl[C_], shf[C_];
  __shared__ float red[16][C_];
  if (threadIdx.x < C_) {
    int c = threadIdx.x;
    float s = 0.f, s2 = 0.f;
#pragma unroll
    for (int u = 0; u < 8; ++u) {
      s += stat[c * 8 + u];
      s2 += stat[C_ * 8 + c * 8 + u];
    }
    const float invM = 1.f / (float)(BN_ * K1_);
    float m = s * invM;
    float v = s2 * invM - m * m;
    float sc = g[c] * rsqrtf(v + EPS_);
    scl[c] = sc;
    shf[c] = bb[c] - m * sc;
  }
  __syncthreads();
  int cq = threadIdx.x & 15, rr = threadIdx.x >> 4;
  int c0 = cq * 4;
  int row0 = blockIdx.x * 64;
  int b = blockIdx.x >> 8;
  float a0 = 0.f, a1 = 0.f, a2 = 0.f, a3 = 0.f;
#pragma unroll
  for (int i = 0; i < 4; ++i) {
    int row = row0 + rr * 4 + i;
    ushort4 u = *(const ushort4*)&y5[(size_t)row * C_ + c0];
    a0 += fmaxf(fmaf(bf2f(u.x), scl[c0 + 0], shf[c0 + 0]), 0.f);
    a1 += fmaxf(fmaf(bf2f(u.y), scl[c0 + 1], shf[c0 + 1]), 0.f);
    a2 += fmaxf(fmaf(bf2f(u.z), scl[c0 + 2], shf[c0 + 2]), 0.f);
    a3 += fmaxf(fmaf(bf2f(u.w), scl[c0 + 3], shf[c0 + 3]), 0.f);
  }
  red[rr][c0 + 0] = a0;
  red[rr][c0 + 1] = a1;
  red[rr][c0 + 2] = a2;
  red[rr][c0 + 3] = a3;
  __syncthreads();
  if (threadIdx.x < C_) {
    float s = 0.f;
#pragma unroll
    for (int r = 0; r < 16; ++r) s += red[r][threadIdx.x];
    atomicAdd(&pooled[(b * C_ + threadIdx.x) * 8 + (blockIdx.x & 7)], s);
  }
}

// ---------------- head ---------------------------------------------------------
__global__ void k_final(const float* __restrict__ pooled, const float* __restrict__ wq,
                        const float* __restrict__ bq, const float* __restrict__ wt,
                        const float* __restrict__ bt, const float* __restrict__ qc,
                        const float* __restrict__ tc, float* __restrict__ out) {
  int b = threadIdx.x;
  if (b >= B_) return;
  float P[C_];
#pragma unroll
  for (int c = 0; c < C_; ++c) {
    float s = 0.f;
#pragma unroll
    for (int u = 0; u < 8; ++u) s += pooled[(b * C_ + c) * 8 + u];
    P[c] = s;
  }
  float qd[4];
#pragma unroll
  for (int i = 0; i < 4; ++i) {
    float s = bq[i];
#pragma unroll
    for (int c = 0; c < C_; ++c) s = fmaf(P[c], wq[i * C_ + c], s);
    qd[i] = s;
  }
  float td[3];
#pragma unroll
  for (int i = 0; i < 3; ++i) {
    float s = bt[i];
#pragma unroll
    for (int c = 0; c < C_; ++c) s = fmaf(P[c], wt[i * C_ + c], s);
    td[i] = s;
  }
  float nq = sqrtf(qd[0] * qd[0] + qd[1] * qd[1] + qd[2] * qd[2] + qd[3] * qd[3]) + 1e-10f;
#pragma unroll
  for (int i = 0; i < 4; ++i) qd[i] /= nq;
  float cw = qc[b * 4 + 0], cx = qc[b * 4 + 1], cyy = qc[b * 4 + 2], cz = qc[b * 4 + 3];
  float qnw = qd[0] * cw - qd[1] * cx - qd[2] * cyy - qd[3] * cz;
  float qnx = qd[0] * cx + qd[1] * cw + qd[2] * cz - qd[3] * cyy;
  float qny = qd[0] * cyy - qd[1] * cz + qd[2] * cw + qd[3] * cx;
  float qnz = qd[0] * cz + qd[1] * cyy - qd[2] * cx + qd[3] * cw;
  float nn = sqrtf(qnw * qnw + qnx * qnx + qny * qny + qnz * qnz) + 1e-10f;
  float vx = tc[b * 3 + 0], vy = tc[b * 3 + 1], vz = tc[b * 3 + 2];
  float aw = -(qd[1] * vx + qd[2] * vy + qd[3] * vz);
  float ax = qd[0] * vx + qd[2] * vz - qd[3] * vy;
  float ay = qd[0] * vy - qd[1] * vz + qd[3] * vx;
  float az = qd[0] * vz + qd[1] * vy - qd[2] * vx;
  float n2 = qd[0] * qd[0] + qd[1] * qd[1] + qd[2] * qd[2] + qd[3] * qd[3] + 1e-10f;
  float bw = qd[0] / n2, bx = -qd[1] / n2, by = -qd[2] / n2, bz = -qd[3] / n2;
  float rx = aw * bx + ax * bw + ay * bz - az * by;
  float ry = aw * by - ax * bz + ay * bw + az * bx;
  float rz = aw * bz + ax * by - ay * bx + az * bw;
  out[b * 7 + 0] = qnw / nn;
  out[b * 7 + 1] = qnx / nn;
  out[b * 7 + 2] = qny / nn;
  out[b * 7 + 3] = qnz / nn;
  out[b * 7 + 4] = rx + td[0];
  out[b * 7 + 5] = ry + td[1];
  out[b * 7 + 6] = rz + td[2];
}

extern "C" void kernel_launch(void* const* d_in, const int* in_sizes, int n_in,
                              void* d_out, int out_size, void* d_ws, size_t ws_size,
                              hipStream_t stream) {
  const float* pos1 = (const float*)d_in[0];
  const float* pos2 = (const float*)d_in[1];
  const float* feat1 = (const float*)d_in[2];
  const float* feat2 = (const float*)d_in[3];
  const float* qc = (const float*)d_in[4];
  const float* tc = (const float*)d_in[5];
  const float* w1_0 = (const float*)d_in[6];
  const float* g1_0 = (const float*)d_in[7];
  const float* b1_0 = (const float*)d_in[8];
  const float* w1_1 = (const float*)d_in[9];
  const float* g1_1 = (const float*)d_in[10];
  const float* b1_1 = (const float*)d_in[11];
  const float* w1_2 = (const float*)d_in[12];
  const float* g1_2 = (const float*)d_in[13];
  const float* b1_2 = (const float*)d_in[14];
  const float* w2_0 = (const float*)d_in[15];
  const float* g2_0 = (const float*)d_in[16];
  const float* b2_0 = (const float*)d_in[17];
  const float* w2_1 = (const float*)d_in[18];
  const float* g2_1 = (const float*)d_in[19];
  const float* b2_1 = (const float*)d_in[20];
  const float* wq = (const float*)d_in[21];
  const float* bq = (const float*)d_in[22];
  const float* wt = (const float*)d_in[23];
  const float* bt = (const float*)d_in[24];

  float* ws = (float*)d_ws;
  const size_t off_stat = 0;          // 8192
  const size_t off_pool = 8192;       // 2048
  const size_t off_wb = 10240;        // 26624
  const size_t off_pts4w = 36864;     // 65536
  const size_t off_pts4p = 102400;    // 65536
  const size_t off_pairW = 167936;    // 65536
  const size_t off_pairP = 233472;    // 65536
  const size_t off_knnK = 299008;     // 1572864 ints
  const size_t off_idxM1 = 1871872;   // 98304 ints
  const size_t off_idxM2 = 1970176;   // 65536 ints
  const size_t off_P2a = 2035712;     // 1048576 (bf16 16384x128)
  const size_t off_P1a = 3084288;     // 1048576
  const size_t off_P1b = 4132864;     // 1048576
  const size_t off_Pfe = 5181440;     // 1048576
  const size_t off_yA = 6230016;      // 3145728 (98304x64 bf16)
  const size_t off_yB = 9375744;      // 3145728

  float* stat0 = ws + off_stat;  // 128*16
  float* stat1 = stat0 + 2048;   // 64*16
  float* stat2 = stat1 + 1024;   // 64*16
  float* stat3 = stat2 + 1024;   // 128*16
  float* stat4 = stat3 + 2048;   // 64*16
  float* pooled = ws + off_pool;
  unsigned short* Wf2a = (unsigned short*)(ws + off_wb);  // 128x64
  unsigned short* Wf1a = Wf2a + 8192;                     // 128x64
  unsigned short* Wfe = Wf1a + 8192;                      // 128x64
  unsigned short* Wf1b = Wfe + 8192;                      // 128x64
  unsigned short* wb1 = Wf1b + 8192;                      // 64x128
  unsigned short* wb2 = wb1 + 8192;                       // 64x64
  unsigned short* wb4 = wb2 + 4096;                       // 64x128
  float4* pts4w = (float4*)(ws + off_pts4w);
  float4* pts4p = (float4*)(ws + off_pts4p);
  float4* pairW = (float4*)(ws + off_pairW);
  float4* pairP = (float4*)(ws + off_pairP);
  int* knnK = (int*)(ws + off_knnK);
  int* idxM1 = (int*)(ws + off_idxM1);
  int* idxM2 = (int*)(ws + off_idxM2);
  unsigned short* P2a = (unsigned short*)(ws + off_P2a);
  unsigned short* P1a = (unsigned short*)(ws + off_P1a);
  unsigned short* P1b = (unsigned short*)(ws + off_P1b);
  unsigned short* Pfe = (unsigned short*)(ws + off_Pfe);
  unsigned short* yA = (unsigned short*)(ws + off_yA);
  unsigned short* yB = (unsigned short*)(ws + off_yB);

  k_init<<<dim3(64, 9), 256, 0, stream>>>(w1_0, w1_1, w1_2, w2_0, w2_1, Wf2a, Wf1a,
                                          Wfe, Wf1b, wb1, wb2, wb4, pos1, pos2, qc, tc,
                                          pts4w, pts4p, pairW, pairP, ws + off_stat);

  k_knnproj<<<dim3(768 + 1024), 256, 0, stream>>>(pts4w, pairW, pairP, knnK, feat2,
                                                  Wf2a, P2a, feat1, Wf1a, P1a, Wf1b,
                                                  P1b);

  // MLP1: stat-only pass over y0, then fused gather-GEMM
  k_stat0<K2_><<<dim3(98304 / 128), 256, 0, stream>>>(w1_0, pts4p, pts4w, P2a, P1a,
                                                      knnK, idxM1, stat0);
  k_layerG<K2_><<<dim3(98304 / 64), 256, 0, stream>>>(
      wb1, w1_0, pts4p, pts4w, P2a, P1a, idxM1, stat0, g1_0, b1_0, 1.f / 98304.f, yA,
      stat1);
  // MLP1 L2: 64->64
  k_layer64<<<dim3(98304 / 64), 256, 0, stream>>>(wb2, yA, stat1, g1_1, b1_1,
                                                  1.f / 98304.f, yB, stat2);
  // fused fe + Pfe projection
  k_feproj<<<dim3(256), 256, 0, stream>>>(yB, stat2, g1_2, b1_2, Wfe, Pfe);
  // MLP2: stat-only pass then fused gather-GEMM
  k_stat0<K1_><<<dim3(65536 / 128), 256, 0, stream>>>(
      w2_0, pts4w, pts4w, Pfe, P1b, knnK + (size_t)BN_ * NCH_ * 6, idxM2, stat3);
  k_layerG<K1_><<<dim3(65536 / 64), 256, 0, stream>>>(
      wb4, w2_0, pts4w, pts4w, Pfe, P1b, idxM2, stat3, g2_0, b2_0, 1.f / 65536.f, yA,
      stat4);
  // pooled
  k_pooled<<<dim3(65536 / 64), 256, 0, stream>>>(yA, stat4, g2_1, b2_1, pooled);
  // head
  k_final<<<dim3(1), 64, 0, stream>>>(pooled, wq, bq, wt, bt, qc, tc, (float*)d_out);
}